// Round 11
// baseline (146.389 us; speedup 1.0000x reference)
//
#include <hip/hip_runtime.h>
#include <math.h>

// Problem: B=4, L=1024, C1=1024, C2=1024, K=32, K_IN=32, g=256.
// N = B*L = 4096 rows. All f32.
//
// ws layout (floats):
//   wT      [1024*1024]            off 0
//   whl     [524288 f32-equiv]     off 1048576  (bf16 hi/lo split weights, 2MB)
//   xc      [2][4096*256]          off 1572864
//   partials[256][4][256]          off 3670016
//   sc      [2][2][256]            off 3932160
//   logits  [8192][1024]           off 3933184
//   tidx    [8192][32] (u32)       off 12321792
//   tval    [8192][32]             off 12583936
//   dresp   [2][4096][32]          off 12846080  (k-half partial out-branch dots)
// total ~13.1M floats = 52.4 MB

typedef __attribute__((ext_vector_type(8))) short short8;
typedef __attribute__((ext_vector_type(4))) float f32x4;

__device__ __forceinline__ unsigned int ford(float f) {
    unsigned int b = __float_as_uint(f);
    return (b & 0x80000000u) ? ~b : (b | 0x80000000u);
}

// ---------------- fused prep: W transpose + lin_w bf16-split + conv/stats ----
// blocks [0,1024): transpose 32x32 tile of W -> wT
// blocks [1024,1280): split so/si lin_w into bf16 hi/lo MFMA B-fragments
// blocks [1280,1536): grouped conv (both branches) + BN partial stats
__global__ __launch_bounds__(256) void prep_k(
    const float* __restrict__ W,
    const float* __restrict__ so_lw, const float* __restrict__ si_lw,
    const float* __restrict__ x,
    const float* __restrict__ so_cw, const float* __restrict__ so_cb,
    const float* __restrict__ si_cw, const float* __restrict__ si_cb,
    float* __restrict__ wT, unsigned short* __restrict__ whl,
    float* __restrict__ xc, float* __restrict__ partials) {
    int bid = blockIdx.x;
    int t = threadIdx.x;
    if (bid < 1024) {
        __shared__ float tile[32][33];
        int c0 = (bid & 31) * 32, r0 = (bid >> 5) * 32;
        int tx = t & 31, ty = t >> 5;  // ty 0..7
#pragma unroll
        for (int i = 0; i < 32; i += 8)
            tile[ty + i][tx] = W[(size_t)(r0 + ty + i) * 1024 + c0 + tx];
        __syncthreads();
#pragma unroll
        for (int i = 0; i < 32; i += 8)
            wT[(size_t)(c0 + ty + i) * 1024 + r0 + tx] = tile[tx][ty + i];
    } else if (bid < 1280) {
        int g = (bid - 1024) * 256 + t;  // 0..65535
        int br = g >> 15;
        int rem = g & 32767;
        int ct = rem >> 9;
        int kt = (rem >> 6) & 7;
        int l  = rem & 63;
        int col = ct * 16 + (l & 15);
        int ks  = kt * 32 + (l >> 4) * 8;
        const float* lw = (br ? si_lw : so_lw) + (size_t)col * 256 + ks;
        float4 v0 = *(const float4*)lw;
        float4 v1 = *(const float4*)(lw + 4);
        unsigned hh[8], ll[8];
#pragma unroll
        for (int j = 0; j < 8; ++j) {
            float a = j < 4 ? (&v0.x)[j] : (&v1.x)[j - 4];
            unsigned b = __float_as_uint(a);
            unsigned rh = (b + 0x7FFFu + ((b >> 16) & 1u)) & 0xFFFF0000u;
            hh[j] = rh >> 16;
            float res = a - __uint_as_float(rh);
            unsigned c = __float_as_uint(res);
            unsigned rl = (c + 0x7FFFu + ((c >> 16) & 1u)) & 0xFFFF0000u;
            ll[j] = rl >> 16;
        }
        uint4 ph, pl;
        ph.x = hh[0] | (hh[1] << 16); ph.y = hh[2] | (hh[3] << 16);
        ph.z = hh[4] | (hh[5] << 16); ph.w = hh[6] | (hh[7] << 16);
        pl.x = ll[0] | (ll[1] << 16); pl.y = ll[2] | (ll[3] << 16);
        pl.z = ll[4] | (ll[5] << 16); pl.w = ll[6] | (ll[7] << 16);
        size_t base = (((((size_t)br * 2 + 0) * 64 + ct) * 8 + kt) * 64 + l) * 8;
        size_t hstride = (size_t)64 * 8 * 64 * 8;
        *(uint4*)&whl[base]           = ph;
        *(uint4*)&whl[base + hstride] = pl;
    } else {
        int g = t;                     // channel 0..255
        int n0 = (bid - 1280) * 16;    // 256 blocks x 16 rows
        float4 wo = ((const float4*)so_cw)[g]; float bo = so_cb[g];
        float4 wi = ((const float4*)si_cw)[g]; float bi = si_cb[g];
        float so_s = 0.f, so_q = 0.f, si_s = 0.f, si_q = 0.f;
#pragma unroll
        for (int r = 0; r < 16; ++r) {
            int n = n0 + r;
            float4 xv = ((const float4*)x)[n * 256 + g];
            float co = fmaf(xv.x, wo.x, fmaf(xv.y, wo.y, fmaf(xv.z, wo.z, fmaf(xv.w, wo.w, bo))));
            float ci = fmaf(xv.x, wi.x, fmaf(xv.y, wi.y, fmaf(xv.z, wi.z, fmaf(xv.w, wi.w, bi))));
            xc[n * 256 + g] = co;
            xc[1048576 + n * 256 + g] = ci;
            so_s += co; so_q += co * co;
            si_s += ci; si_q += ci * ci;
        }
        int b = bid - 1280;
        partials[(b * 4 + 0) * 256 + g] = so_s;
        partials[(b * 4 + 1) * 256 + g] = so_q;
        partials[(b * 4 + 2) * 256 + g] = si_s;
        partials[(b * 4 + 3) * 256 + g] = si_q;
    }
}

// ---------------- finalize BN stats -> per-channel scale/shift ---------------
__global__ __launch_bounds__(256) void stats_k(
    const float* __restrict__ partials,
    const float* __restrict__ g_so, const float* __restrict__ b_so,
    const float* __restrict__ g_si, const float* __restrict__ b_si,
    float* __restrict__ sc) {
    int g = threadIdx.x;
    int br = blockIdx.x;  // 0 = so, 1 = si
    float s = 0.f, q = 0.f;
    for (int b = 0; b < 256; ++b) {
        s += partials[(b * 4 + br * 2 + 0) * 256 + g];
        q += partials[(b * 4 + br * 2 + 1) * 256 + g];
    }
    float mean = s * (1.f / 4096.f);
    float var  = q * (1.f / 4096.f) - mean * mean;  // biased, matches ref
    float rstd = rsqrtf(var + 1e-5f);
    float gm = br ? g_si[g] : g_so[g];
    float bt = br ? b_si[g] : b_so[g];
    float scale = gm * rstd;
    sc[br * 512 + g]       = scale;
    sc[br * 512 + 256 + g] = fmaf(-mean, scale, bt);
}

// ---------------- BN+GELU fused + bf16x4-split MFMA logits GEMM --------------
__global__ __launch_bounds__(256, 2) void logits_mfma_k(
    const float* __restrict__ xc, const float* __restrict__ sc,
    const unsigned short* __restrict__ whl,
    const float* __restrict__ so_lb, const float* __restrict__ si_lb,
    float* __restrict__ logits) {
    __shared__ unsigned short ah[2048 * 8];  // 32 KB
    __shared__ unsigned short al[2048 * 8];  // 32 KB
    int t = threadIdx.x;
    int n0 = blockIdx.x * 64;
    int cb = blockIdx.y;          // 256-col block
    int br = blockIdx.z;
    int wave = t >> 6, lane = t & 63;

    const float* xcb = xc + (size_t)br * 1048576;
    const float* scp = sc + br * 512;

#pragma unroll
    for (int i = 0; i < 8; ++i) {
        int s = t + 256 * i;
        int rt = s >> 9, kt = (s >> 6) & 7, l = s & 63;
        int row = n0 + rt * 16 + (l & 15);
        int ks = kt * 32 + (l >> 4) * 8;
        const float* xp = xcb + (size_t)row * 256 + ks;
        float4 c0 = *(const float4*)xp;
        float4 c1 = *(const float4*)(xp + 4);
        float4 s0 = *(const float4*)(scp + ks);
        float4 s1 = *(const float4*)(scp + ks + 4);
        float4 h0 = *(const float4*)(scp + 256 + ks);
        float4 h1 = *(const float4*)(scp + 256 + ks + 4);
        unsigned hh[8], ll[8];
#pragma unroll
        for (int j = 0; j < 8; ++j) {
            float cv  = j < 4 ? (&c0.x)[j] : (&c1.x)[j - 4];
            float scl = j < 4 ? (&s0.x)[j] : (&s1.x)[j - 4];
            float shf = j < 4 ? (&h0.x)[j] : (&h1.x)[j - 4];
            float z = fmaf(cv, scl, shf);
            float a = 0.5f * z * (1.f + erff(z * 0.70710678f));
            unsigned b = __float_as_uint(a);
            unsigned rh = (b + 0x7FFFu + ((b >> 16) & 1u)) & 0xFFFF0000u;
            hh[j] = rh >> 16;
            float res = a - __uint_as_float(rh);
            unsigned cc = __float_as_uint(res);
            unsigned rl = (cc + 0x7FFFu + ((cc >> 16) & 1u)) & 0xFFFF0000u;
            ll[j] = rl >> 16;
        }
        uint4 ph, pl;
        ph.x = hh[0] | (hh[1] << 16); ph.y = hh[2] | (hh[3] << 16);
        ph.z = hh[4] | (hh[5] << 16); ph.w = hh[6] | (hh[7] << 16);
        pl.x = ll[0] | (ll[1] << 16); pl.y = ll[2] | (ll[3] << 16);
        pl.z = ll[4] | (ll[5] << 16); pl.w = ll[6] | (ll[7] << 16);
        *(uint4*)&ah[(size_t)s * 8] = ph;
        *(uint4*)&al[(size_t)s * 8] = pl;
    }
    __syncthreads();

    f32x4 acc[4][4];  // [ci][rt]
#pragma unroll
    for (int ci = 0; ci < 4; ++ci)
#pragma unroll
        for (int rt = 0; rt < 4; ++rt) acc[ci][rt] = (f32x4){0.f, 0.f, 0.f, 0.f};

    const size_t hstride = (size_t)64 * 8 * 64 * 8;
#pragma unroll 2
    for (int kt = 0; kt < 8; ++kt) {
        short8 Ah[4], Al[4];
#pragma unroll
        for (int rt = 0; rt < 4; ++rt) {
            Ah[rt] = *(const short8*)&ah[(((rt * 8 + kt) * 64) + lane) * 8];
            Al[rt] = *(const short8*)&al[(((rt * 8 + kt) * 64) + lane) * 8];
        }
#pragma unroll
        for (int ci = 0; ci < 4; ++ci) {
            int ctg = cb * 16 + wave * 4 + ci;
            size_t boff = ((((size_t)br * 2 + 0) * 64 + ctg) * 8 + kt) * 64 * 8 +
                          (size_t)lane * 8;
            short8 Wh = *(const short8*)&whl[boff];
            short8 Wl = *(const short8*)&whl[boff + hstride];
#pragma unroll
            for (int rt = 0; rt < 4; ++rt) {
                acc[ci][rt] = __builtin_amdgcn_mfma_f32_16x16x32_bf16(Ah[rt], Wh, acc[ci][rt], 0, 0, 0);
                acc[ci][rt] = __builtin_amdgcn_mfma_f32_16x16x32_bf16(Ah[rt], Wl, acc[ci][rt], 0, 0, 0);
                acc[ci][rt] = __builtin_amdgcn_mfma_f32_16x16x32_bf16(Al[rt], Wh, acc[ci][rt], 0, 0, 0);
                acc[ci][rt] = __builtin_amdgcn_mfma_f32_16x16x32_bf16(Al[rt], Wl, acc[ci][rt], 0, 0, 0);
            }
        }
    }

    const float* lb = br ? si_lb : so_lb;
#pragma unroll
    for (int ci = 0; ci < 4; ++ci) {
        int colg = cb * 256 + (wave * 4 + ci) * 16 + (lane & 15);
        float lbv = lb[colg];
#pragma unroll
        for (int rt = 0; rt < 4; ++rt) {
#pragma unroll
            for (int i = 0; i < 4; ++i) {
                int row = n0 + rt * 16 + (lane >> 4) * 4 + i;
                logits[((size_t)br * 4096 + row) * 1024 + colg] = acc[ci][rt][i] + lbv;
            }
        }
    }
}

// ---------------- softmax stats + exact top-32 per row-branch ----------------
__global__ __launch_bounds__(256) void topk_k(const float* __restrict__ logits,
                                              unsigned int* __restrict__ tidx,
                                              float* __restrict__ tval) {
    __shared__ unsigned int hist[4][256];
    __shared__ unsigned int wcnt[4];
    int wave = threadIdx.x >> 6, lane = threadIdx.x & 63;
    int rb = blockIdx.x * 4 + wave;  // 0..8191
    unsigned int* h = hist[wave];

    const float4* lg = (const float4*)(logits + (size_t)rb * 1024);
    float v[16];
#pragma unroll
    for (int q = 0; q < 4; ++q) {
        float4 f = lg[q * 64 + lane];
        v[q * 4 + 0] = f.x; v[q * 4 + 1] = f.y;
        v[q * 4 + 2] = f.z; v[q * 4 + 3] = f.w;
    }
    float rmax = v[0];
#pragma unroll
    for (int i = 1; i < 16; ++i) rmax = fmaxf(rmax, v[i]);
#pragma unroll
    for (int s = 32; s; s >>= 1) rmax = fmaxf(rmax, __shfl_xor(rmax, s));
    float rsum = 0.f;
#pragma unroll
    for (int i = 0; i < 16; ++i) rsum += __expf(v[i] - rmax);
#pragma unroll
    for (int s = 32; s; s >>= 1) rsum += __shfl_xor(rsum, s);

    unsigned int kb[16];
#pragma unroll
    for (int i = 0; i < 16; ++i) kb[i] = ford(v[i]);

    unsigned inmask = 0xFFFFu;
    unsigned need = 32, prefix = 0, lasth = 0;
#pragma unroll
    for (int level = 0; level < 3; ++level) {
        int shift = 24 - level * 8;
        ((uint4*)h)[lane] = make_uint4(0u, 0u, 0u, 0u);
        __syncthreads();
#pragma unroll
        for (int i = 0; i < 16; ++i)
            if ((inmask >> i) & 1u) atomicAdd(&h[(kb[i] >> shift) & 0xFFu], 1u);
        __syncthreads();
        uint4 hv = ((const uint4*)h)[lane];
        unsigned sl = hv.x + hv.y + hv.z + hv.w;
        unsigned S = sl;
#pragma unroll
        for (int off = 1; off < 64; off <<= 1) {
            unsigned o = __shfl_down(S, off);
            if (lane + off < 64) S += o;
        }
        unsigned above = S - sl;
        unsigned cg3 = above + hv.w;
        unsigned cg2 = cg3 + hv.z;
        unsigned cg1 = cg2 + hv.y;
        unsigned cg0 = cg1 + hv.x;
        unsigned pack = 0;
        if      (cg3 >= need) pack = ((4u * lane + 3u) << 12) | cg3;
        else if (cg2 >= need) pack = ((4u * lane + 2u) << 12) | cg2;
        else if (cg1 >= need) pack = ((4u * lane + 1u) << 12) | cg1;
        else if (cg0 >= need) pack = ((4u * lane + 0u) << 12) | cg0;
#pragma unroll
        for (int s = 32; s; s >>= 1) {
            unsigned o = __shfl_xor(pack, s);
            pack = o > pack ? o : pack;
        }
        unsigned bstar = pack >> 12, cstar = pack & 0xFFFu;
        unsigned hstar = h[bstar];
        need -= (cstar - hstar);
        prefix = (prefix << 8) | bstar;
        lasth = hstar;
        unsigned nm = 0;
#pragma unroll
        for (int i = 0; i < 16; ++i)
            if (((inmask >> i) & 1u) && ((kb[i] >> shift) & 0xFFu) == bstar)
                nm |= 1u << i;
        inmask = nm;
        __syncthreads();
    }

    unsigned winmask = 0;
    if (lasth == need) {
        winmask = inmask;
    } else {
        unsigned avail = inmask;
        unsigned long long best = 0ULL;
#pragma unroll
        for (int i = 0; i < 16; ++i)
            if ((avail >> i) & 1u) {
                int j = (i >> 2) * 256 + lane * 4 + (i & 3);
                unsigned long long k64 =
                    ((unsigned long long)kb[i] << 32) | (unsigned int)(~j);
                best = k64 > best ? k64 : best;
            }
        for (unsigned k = 0; k < need; ++k) {
            unsigned long long w = best;
#pragma unroll
            for (int s = 32; s; s >>= 1) {
                unsigned long long o = __shfl_xor(w, s);
                if (o > w) w = o;
            }
            if (best == w) {
                unsigned long long nb = 0ULL;
#pragma unroll
                for (int i = 0; i < 16; ++i)
                    if ((avail >> i) & 1u) {
                        int j = (i >> 2) * 256 + lane * 4 + (i & 3);
                        unsigned long long k64 =
                            ((unsigned long long)kb[i] << 32) | (unsigned int)(~j);
                        if (k64 == w) { winmask |= 1u << i; avail &= ~(1u << i); }
                        else nb = k64 > nb ? k64 : nb;
                    }
                best = nb;
            }
        }
    }

    if (lane == 0) wcnt[wave] = 0;
#pragma unroll
    for (int i = 0; i < 16; ++i) {
        bool wn = ((kb[i] >> 8) > prefix) || ((winmask >> i) & 1u);
        if (wn) {
            unsigned slot = atomicAdd(&wcnt[wave], 1u);
            int j = (i >> 2) * 256 + lane * 4 + (i & 3);
            tidx[(size_t)rb * 32 + slot] = (unsigned int)j;
            tval[(size_t)rb * 32 + slot] = __expf(v[i] - rmax) / rsum;
        }
    }
}

// ---------------- final pass A (per k-half): partial out-branch dots ---------
// dresp[kh][n][d] = dot(x[n][kh*512:+512], wT[gidx[d]][kh*512:+512]).
// Weight working set per launch = 2 MB (half of per-XCD L2) -> L2-resident.
__global__ __launch_bounds__(256) void finalA_k(
    const float* __restrict__ x, const float* __restrict__ wT,
    const unsigned int* __restrict__ tidx, int kh,
    float* __restrict__ dresp) {
    int n = blockIdx.x, t = threadIdx.x, wave = t >> 6, lane = t & 63;
    __shared__ float xr[512];
    __shared__ unsigned int gidx[32];

    if (t < 128) ((float4*)xr)[t] = ((const float4*)(x + (size_t)n * 1024 + kh * 512))[t];
    else if (t < 160) gidx[t - 128] = tidx[(size_t)n * 32 + (t - 128)];
    __syncthreads();

    const float4* xr4 = (const float4*)xr;
#pragma unroll
    for (int d8 = 0; d8 < 8; ++d8) {
        int d = wave * 8 + d8;
        const float4* wrow = (const float4*)(wT + (size_t)gidx[d] * 1024 + kh * 512);
        float s = 0.f;
#pragma unroll
        for (int q = 0; q < 2; ++q) {
            float4 a = wrow[q * 64 + lane];
            float4 b = xr4[q * 64 + lane];
            s += a.x * b.x + a.y * b.y + a.z * b.z + a.w * b.w;
        }
#pragma unroll
        for (int sft = 32; sft; sft >>= 1) s += __shfl_xor(s, sft);
        if (lane == 0) dresp[((size_t)kh * 4096 + n) * 32 + d] = s;
    }
}

// ---------------- final pass B (per col-half): in-branch axpy + assemble -----
// out[n][jb:jb+512] = bias + sum_k ival_k*W[iidx_k][jb:+512] + scatter(dres).
// Weight working set per launch = 2 MB -> L2-resident.
__global__ __launch_bounds__(256) void finalB_k(
    const float* __restrict__ x, const float* __restrict__ W,
    const float* __restrict__ bias,
    const unsigned int* __restrict__ tidx, const float* __restrict__ tval,
    const float* __restrict__ dresp, int ch, float* __restrict__ out) {
    int n = blockIdx.x, t = threadIdx.x;
    int jb = ch * 512;
    __shared__ float xr[512];
    __shared__ unsigned int iidx[32]; __shared__ float ival[32];
    __shared__ unsigned int gidx[32]; __shared__ float dr[32];

    if (t < 32) {
        unsigned c = tidx[((size_t)4096 + n) * 32 + t];
        iidx[t] = c;
        ival[t] = tval[((size_t)4096 + n) * 32 + t] * x[(size_t)n * 1024 + c];
    } else if (t < 64) {
        int k = t - 32;
        gidx[k] = tidx[(size_t)n * 32 + k];
        dr[k] = (dresp[(size_t)n * 32 + k] + dresp[((size_t)4096 + n) * 32 + k]) *
                tval[(size_t)n * 32 + k];
    }
    __syncthreads();

    float2 acc = ((const float2*)(bias + jb))[t];
    for (int k = 0; k < 32; ++k) {
        float g = ival[k];
        float2 wr = ((const float2*)(W + (size_t)iidx[k] * 1024 + jb))[t];
        acc.x = fmaf(g, wr.x, acc.x);
        acc.y = fmaf(g, wr.y, acc.y);
    }
    ((float2*)xr)[t] = acc;
    __syncthreads();
    if (t < 32) {
        int c = (int)gidx[t] - jb;
        if (0 <= c && c < 512) xr[c] += dr[t];  // unique indices, no race
    }
    __syncthreads();
    ((float2*)(out + (size_t)n * 1024 + jb))[t] = ((float2*)xr)[t];
}

extern "C" void kernel_launch(void* const* d_in, const int* in_sizes, int n_in,
                              void* d_out, int out_size, void* d_ws, size_t ws_size,
                              hipStream_t stream) {
    (void)in_sizes; (void)n_in; (void)out_size; (void)ws_size;
    const float* x        = (const float*)d_in[0];
    const float* W        = (const float*)d_in[1];
    const float* bias     = (const float*)d_in[2];
    const float* so_cw    = (const float*)d_in[3];
    const float* so_cb    = (const float*)d_in[4];
    const float* so_gm    = (const float*)d_in[5];
    const float* so_bt    = (const float*)d_in[6];
    const float* so_lw    = (const float*)d_in[7];
    const float* so_lb    = (const float*)d_in[8];
    const float* si_cw    = (const float*)d_in[9];
    const float* si_cb    = (const float*)d_in[10];
    const float* si_gm    = (const float*)d_in[11];
    const float* si_bt    = (const float*)d_in[12];
    const float* si_lw    = (const float*)d_in[13];
    const float* si_lb    = (const float*)d_in[14];
    float* out = (float*)d_out;

    float* ws       = (float*)d_ws;
    float* wT       = ws;                       // 1048576
    unsigned short* whl = (unsigned short*)(ws + 1048576);  // 1048576 ushorts = 2MB
    float* xc       = ws + 1572864;             // 2 x 1048576
    float* partials = ws + 3670016;             // 262144
    float* sc       = ws + 3932160;             // 1024
    float* logits   = ws + 3933184;             // 8388608
    unsigned int* tidx = (unsigned int*)(ws + 12321792);  // 262144
    float* tval     = ws + 12583936;            // 262144
    float* dresp    = ws + 12846080;            // 2 x 131072

    prep_k<<<1536, 256, 0, stream>>>(W, so_lw, si_lw, x, so_cw, so_cb, si_cw, si_cb,
                                     wT, whl, xc, partials);
    stats_k<<<2, 256, 0, stream>>>(partials, so_gm, so_bt, si_gm, si_bt, sc);
    logits_mfma_k<<<dim3(64, 4, 2), 256, 0, stream>>>(xc, sc, whl, so_lb, si_lb, logits);
    topk_k<<<2048, 256, 0, stream>>>(logits, tidx, tval);
    finalA_k<<<4096, 256, 0, stream>>>(x, wT, tidx, 0, dresp);
    finalA_k<<<4096, 256, 0, stream>>>(x, wT, tidx, 1, dresp);
    finalB_k<<<4096, 256, 0, stream>>>(x, W, bias, tidx, tval, dresp, 0, out);
    finalB_k<<<4096, 256, 0, stream>>>(x, W, bias, tidx, tval, dresp, 1, out);
}

// Round 12
// 128.220 us; speedup vs baseline: 1.1417x; 1.1417x over previous
//
#include <hip/hip_runtime.h>
#include <math.h>

// Problem: B=4, L=1024, C1=1024, C2=1024, K=32, K_IN=32, g=256.
// N = B*L = 4096 rows. All f32.
//
// ws layout (floats):
//   wT      [1024*1024]            off 0
//   whl     [524288 f32-equiv]     off 1048576  (bf16 hi/lo split lin_w, 2MB)
//   xc      [2][4096*256]          off 1572864
//   partials[256][4][256]          off 3670016
//   sc      [2][2][256]            off 3932160
//   logits  [8192][1024]           off 3933184
//   tidx    [8192][32] (u32)       off 12321792
//   tval    [8192][32]             off 12583936
//   dres    [4096][32]             off 12846080
//   xah     [1048576 f32-equiv]    off 12977152 (bf16 hi xa frags, 4MB)
//   xal     [1048576 f32-equiv]    off 14025728 (bf16 lo xa frags, 4MB)
// total ~15.1M floats = 60.3 MB

typedef __attribute__((ext_vector_type(8))) short short8;
typedef __attribute__((ext_vector_type(4))) float f32x4;

__device__ __forceinline__ unsigned int ford(float f) {
    unsigned int b = __float_as_uint(f);
    return (b & 0x80000000u) ? ~b : (b | 0x80000000u);
}

// ---------------- fused prep: W transpose + lin_w bf16-split + conv/stats ----
__global__ __launch_bounds__(256) void prep_k(
    const float* __restrict__ W,
    const float* __restrict__ so_lw, const float* __restrict__ si_lw,
    const float* __restrict__ x,
    const float* __restrict__ so_cw, const float* __restrict__ so_cb,
    const float* __restrict__ si_cw, const float* __restrict__ si_cb,
    float* __restrict__ wT, unsigned short* __restrict__ whl,
    float* __restrict__ xc, float* __restrict__ partials) {
    int bid = blockIdx.x;
    int t = threadIdx.x;
    if (bid < 1024) {
        __shared__ float tile[32][33];
        int c0 = (bid & 31) * 32, r0 = (bid >> 5) * 32;
        int tx = t & 31, ty = t >> 5;  // ty 0..7
#pragma unroll
        for (int i = 0; i < 32; i += 8)
            tile[ty + i][tx] = W[(size_t)(r0 + ty + i) * 1024 + c0 + tx];
        __syncthreads();
#pragma unroll
        for (int i = 0; i < 32; i += 8)
            wT[(size_t)(c0 + ty + i) * 1024 + r0 + tx] = tile[tx][ty + i];
    } else if (bid < 1280) {
        int g = (bid - 1024) * 256 + t;  // 0..65535
        int br = g >> 15;
        int rem = g & 32767;
        int ct = rem >> 9;
        int kt = (rem >> 6) & 7;
        int l  = rem & 63;
        int col = ct * 16 + (l & 15);
        int ks  = kt * 32 + (l >> 4) * 8;
        const float* lw = (br ? si_lw : so_lw) + (size_t)col * 256 + ks;
        float4 v0 = *(const float4*)lw;
        float4 v1 = *(const float4*)(lw + 4);
        unsigned hh[8], ll[8];
#pragma unroll
        for (int j = 0; j < 8; ++j) {
            float a = j < 4 ? (&v0.x)[j] : (&v1.x)[j - 4];
            unsigned b = __float_as_uint(a);
            unsigned rh = (b + 0x7FFFu + ((b >> 16) & 1u)) & 0xFFFF0000u;
            hh[j] = rh >> 16;
            float res = a - __uint_as_float(rh);
            unsigned c = __float_as_uint(res);
            unsigned rl = (c + 0x7FFFu + ((c >> 16) & 1u)) & 0xFFFF0000u;
            ll[j] = rl >> 16;
        }
        uint4 ph, pl;
        ph.x = hh[0] | (hh[1] << 16); ph.y = hh[2] | (hh[3] << 16);
        ph.z = hh[4] | (hh[5] << 16); ph.w = hh[6] | (hh[7] << 16);
        pl.x = ll[0] | (ll[1] << 16); pl.y = ll[2] | (ll[3] << 16);
        pl.z = ll[4] | (ll[5] << 16); pl.w = ll[6] | (ll[7] << 16);
        size_t base = (((((size_t)br * 2 + 0) * 64 + ct) * 8 + kt) * 64 + l) * 8;
        size_t hstride = (size_t)64 * 8 * 64 * 8;
        *(uint4*)&whl[base]           = ph;
        *(uint4*)&whl[base + hstride] = pl;
    } else {
        int g = t;                     // channel 0..255
        int n0 = (bid - 1280) * 16;    // 256 blocks x 16 rows
        float4 wo = ((const float4*)so_cw)[g]; float bo = so_cb[g];
        float4 wi = ((const float4*)si_cw)[g]; float bi = si_cb[g];
        float so_s = 0.f, so_q = 0.f, si_s = 0.f, si_q = 0.f;
#pragma unroll
        for (int r = 0; r < 16; ++r) {
            int n = n0 + r;
            float4 xv = ((const float4*)x)[n * 256 + g];
            float co = fmaf(xv.x, wo.x, fmaf(xv.y, wo.y, fmaf(xv.z, wo.z, fmaf(xv.w, wo.w, bo))));
            float ci = fmaf(xv.x, wi.x, fmaf(xv.y, wi.y, fmaf(xv.z, wi.z, fmaf(xv.w, wi.w, bi))));
            xc[n * 256 + g] = co;
            xc[1048576 + n * 256 + g] = ci;
            so_s += co; so_q += co * co;
            si_s += ci; si_q += ci * ci;
        }
        int b = bid - 1280;
        partials[(b * 4 + 0) * 256 + g] = so_s;
        partials[(b * 4 + 1) * 256 + g] = so_q;
        partials[(b * 4 + 2) * 256 + g] = si_s;
        partials[(b * 4 + 3) * 256 + g] = si_q;
    }
}

// ---------------- finalize BN stats -> per-channel scale/shift ---------------
__global__ __launch_bounds__(256) void stats_k(
    const float* __restrict__ partials,
    const float* __restrict__ g_so, const float* __restrict__ b_so,
    const float* __restrict__ g_si, const float* __restrict__ b_si,
    float* __restrict__ sc) {
    int g = threadIdx.x;
    int br = blockIdx.x;  // 0 = so, 1 = si
    float s = 0.f, q = 0.f;
    for (int b = 0; b < 256; ++b) {
        s += partials[(b * 4 + br * 2 + 0) * 256 + g];
        q += partials[(b * 4 + br * 2 + 1) * 256 + g];
    }
    float mean = s * (1.f / 4096.f);
    float var  = q * (1.f / 4096.f) - mean * mean;  // biased, matches ref
    float rstd = rsqrtf(var + 1e-5f);
    float gm = br ? g_si[g] : g_so[g];
    float bt = br ? b_si[g] : b_so[g];
    float scale = gm * rstd;
    sc[br * 512 + g]       = scale;
    sc[br * 512 + 256 + g] = fmaf(-mean, scale, bt);
}

// ---------------- BN + exact GELU + bf16 hi/lo split -> xa MFMA A-fragments --
// Computed ONCE per element (the old kernel recomputed it 4x, once per
// col-block, with erff ~30 VALU ops each). Fragment layout (matches R9/R10
// verified staging): slot s = ((br*256+rtg)*8+kt)*64 + l holds
// row = rtg*16 + (l&15), k = kt*32 + (l>>4)*8 + j (8 elems, 16B).
__global__ __launch_bounds__(256) void gelusplit_k(
    const float* __restrict__ xc, const float* __restrict__ sc,
    unsigned short* __restrict__ xah, unsigned short* __restrict__ xal) {
    int s = blockIdx.x * 256 + threadIdx.x;  // 0..262143
    int br  = s >> 17;
    int rem = s & 131071;
    int rtg = rem >> 9;
    int kt  = (rem >> 6) & 7;
    int l   = rem & 63;
    int row = rtg * 16 + (l & 15);
    int ks  = kt * 32 + (l >> 4) * 8;
    const float* xp  = xc + (size_t)br * 1048576 + (size_t)row * 256 + ks;
    const float* scp = sc + br * 512;
    float4 c0 = *(const float4*)xp;
    float4 c1 = *(const float4*)(xp + 4);
    float4 s0 = *(const float4*)(scp + ks);
    float4 s1 = *(const float4*)(scp + ks + 4);
    float4 h0 = *(const float4*)(scp + 256 + ks);
    float4 h1 = *(const float4*)(scp + 256 + ks + 4);
    unsigned hh[8], ll[8];
#pragma unroll
    for (int j = 0; j < 8; ++j) {
        float cv  = j < 4 ? (&c0.x)[j] : (&c1.x)[j - 4];
        float scl = j < 4 ? (&s0.x)[j] : (&s1.x)[j - 4];
        float shf = j < 4 ? (&h0.x)[j] : (&h1.x)[j - 4];
        float z = fmaf(cv, scl, shf);
        float a = 0.5f * z * (1.f + erff(z * 0.70710678f));
        unsigned b = __float_as_uint(a);
        unsigned rh = (b + 0x7FFFu + ((b >> 16) & 1u)) & 0xFFFF0000u;
        hh[j] = rh >> 16;
        float res = a - __uint_as_float(rh);
        unsigned cc = __float_as_uint(res);
        unsigned rl = (cc + 0x7FFFu + ((cc >> 16) & 1u)) & 0xFFFF0000u;
        ll[j] = rl >> 16;
    }
    uint4 ph, pl;
    ph.x = hh[0] | (hh[1] << 16); ph.y = hh[2] | (hh[3] << 16);
    ph.z = hh[4] | (hh[5] << 16); ph.w = hh[6] | (hh[7] << 16);
    pl.x = ll[0] | (ll[1] << 16); pl.y = ll[2] | (ll[3] << 16);
    pl.z = ll[4] | (ll[5] << 16); pl.w = ll[6] | (ll[7] << 16);
    *(uint4*)&xah[(size_t)s * 8] = ph;
    *(uint4*)&xal[(size_t)s * 8] = pl;
}

// ---------------- bf16x4-split MFMA logits GEMM (no LDS, no GELU) ------------
// Per kt: 16 dwordx4 fragment loads (L2-resident) feed 64 MFMAs.
__global__ __launch_bounds__(256, 2) void logits_mfma2_k(
    const unsigned short* __restrict__ xah, const unsigned short* __restrict__ xal,
    const unsigned short* __restrict__ whl,
    const float* __restrict__ so_lb, const float* __restrict__ si_lb,
    float* __restrict__ logits) {
    int t = threadIdx.x;
    int bx = blockIdx.x;          // 64-row block
    int n0 = bx * 64;
    int cb = blockIdx.y;          // 256-col block
    int br = blockIdx.z;
    int wave = t >> 6, lane = t & 63;

    f32x4 acc[4][4];  // [ci][rt]
#pragma unroll
    for (int ci = 0; ci < 4; ++ci)
#pragma unroll
        for (int rt = 0; rt < 4; ++rt) acc[ci][rt] = (f32x4){0.f, 0.f, 0.f, 0.f};

    const size_t hstride = (size_t)64 * 8 * 64 * 8;
#pragma unroll 2
    for (int kt = 0; kt < 8; ++kt) {
        short8 Ah[4], Al[4];
#pragma unroll
        for (int rt = 0; rt < 4; ++rt) {
            size_t aoff = (((size_t)br * 256 + bx * 4 + rt) * 8 + kt) * 512 +
                          (size_t)lane * 8;
            Ah[rt] = *(const short8*)&xah[aoff];
            Al[rt] = *(const short8*)&xal[aoff];
        }
#pragma unroll
        for (int ci = 0; ci < 4; ++ci) {
            int ctg = cb * 16 + wave * 4 + ci;
            size_t boff = ((((size_t)br * 2 + 0) * 64 + ctg) * 8 + kt) * 512 +
                          (size_t)lane * 8;
            short8 Wh = *(const short8*)&whl[boff];
            short8 Wl = *(const short8*)&whl[boff + hstride];
#pragma unroll
            for (int rt = 0; rt < 4; ++rt) {
                acc[ci][rt] = __builtin_amdgcn_mfma_f32_16x16x32_bf16(Ah[rt], Wh, acc[ci][rt], 0, 0, 0);
                acc[ci][rt] = __builtin_amdgcn_mfma_f32_16x16x32_bf16(Ah[rt], Wl, acc[ci][rt], 0, 0, 0);
                acc[ci][rt] = __builtin_amdgcn_mfma_f32_16x16x32_bf16(Al[rt], Wh, acc[ci][rt], 0, 0, 0);
                acc[ci][rt] = __builtin_amdgcn_mfma_f32_16x16x32_bf16(Al[rt], Wl, acc[ci][rt], 0, 0, 0);
            }
        }
    }

    // C/D mapping (HW-verified): col = lane&15, row = (lane>>4)*4 + i
    const float* lb = br ? si_lb : so_lb;
#pragma unroll
    for (int ci = 0; ci < 4; ++ci) {
        int colg = cb * 256 + (wave * 4 + ci) * 16 + (lane & 15);
        float lbv = lb[colg];
#pragma unroll
        for (int rt = 0; rt < 4; ++rt) {
#pragma unroll
            for (int i = 0; i < 4; ++i) {
                int row = n0 + rt * 16 + (lane >> 4) * 4 + i;
                logits[((size_t)br * 4096 + row) * 1024 + colg] = acc[ci][rt][i] + lbv;
            }
        }
    }
}

// ---------------- softmax stats + exact top-32, one wave per row-branch ------
// 64-thread blocks: each wave fully independent (no cross-wave barriers).
__global__ __launch_bounds__(64) void topk_k(const float* __restrict__ logits,
                                             unsigned int* __restrict__ tidx,
                                             float* __restrict__ tval) {
    __shared__ unsigned int hist[256];
    __shared__ unsigned int wcnt;
    int lane = threadIdx.x;
    int rb = blockIdx.x;  // 0..8191
    unsigned int* h = hist;

    const float4* lg = (const float4*)(logits + (size_t)rb * 1024);
    float v[16];
#pragma unroll
    for (int q = 0; q < 4; ++q) {
        float4 f = lg[q * 64 + lane];
        v[q * 4 + 0] = f.x; v[q * 4 + 1] = f.y;
        v[q * 4 + 2] = f.z; v[q * 4 + 3] = f.w;
    }
    float rmax = v[0];
#pragma unroll
    for (int i = 1; i < 16; ++i) rmax = fmaxf(rmax, v[i]);
#pragma unroll
    for (int s = 32; s; s >>= 1) rmax = fmaxf(rmax, __shfl_xor(rmax, s));
    float rsum = 0.f;
#pragma unroll
    for (int i = 0; i < 16; ++i) rsum += __expf(v[i] - rmax);
#pragma unroll
    for (int s = 32; s; s >>= 1) rsum += __shfl_xor(rsum, s);

    unsigned int kb[16];
#pragma unroll
    for (int i = 0; i < 16; ++i) kb[i] = ford(v[i]);

    unsigned inmask = 0xFFFFu;
    unsigned need = 32, prefix = 0, lasth = 0;
#pragma unroll
    for (int level = 0; level < 3; ++level) {
        int shift = 24 - level * 8;
        ((uint4*)h)[lane] = make_uint4(0u, 0u, 0u, 0u);
        __syncthreads();
#pragma unroll
        for (int i = 0; i < 16; ++i)
            if ((inmask >> i) & 1u) atomicAdd(&h[(kb[i] >> shift) & 0xFFu], 1u);
        __syncthreads();
        uint4 hv = ((const uint4*)h)[lane];
        unsigned sl = hv.x + hv.y + hv.z + hv.w;
        unsigned S = sl;
#pragma unroll
        for (int off = 1; off < 64; off <<= 1) {
            unsigned o = __shfl_down(S, off);
            if (lane + off < 64) S += o;
        }
        unsigned above = S - sl;
        unsigned cg3 = above + hv.w;
        unsigned cg2 = cg3 + hv.z;
        unsigned cg1 = cg2 + hv.y;
        unsigned cg0 = cg1 + hv.x;
        unsigned pack = 0;
        if      (cg3 >= need) pack = ((4u * lane + 3u) << 12) | cg3;
        else if (cg2 >= need) pack = ((4u * lane + 2u) << 12) | cg2;
        else if (cg1 >= need) pack = ((4u * lane + 1u) << 12) | cg1;
        else if (cg0 >= need) pack = ((4u * lane + 0u) << 12) | cg0;
#pragma unroll
        for (int s = 32; s; s >>= 1) {
            unsigned o = __shfl_xor(pack, s);
            pack = o > pack ? o : pack;
        }
        unsigned bstar = pack >> 12, cstar = pack & 0xFFFu;
        unsigned hstar = h[bstar];
        need -= (cstar - hstar);
        prefix = (prefix << 8) | bstar;
        lasth = hstar;
        unsigned nm = 0;
#pragma unroll
        for (int i = 0; i < 16; ++i)
            if (((inmask >> i) & 1u) && ((kb[i] >> shift) & 0xFFu) == bstar)
                nm |= 1u << i;
        inmask = nm;
        __syncthreads();
    }

    unsigned winmask = 0;
    if (lasth == need) {
        winmask = inmask;
    } else {
        unsigned avail = inmask;
        unsigned long long best = 0ULL;
#pragma unroll
        for (int i = 0; i < 16; ++i)
            if ((avail >> i) & 1u) {
                int j = (i >> 2) * 256 + lane * 4 + (i & 3);
                unsigned long long k64 =
                    ((unsigned long long)kb[i] << 32) | (unsigned int)(~j);
                best = k64 > best ? k64 : best;
            }
        for (unsigned k = 0; k < need; ++k) {
            unsigned long long w = best;
#pragma unroll
            for (int s = 32; s; s >>= 1) {
                unsigned long long o = __shfl_xor(w, s);
                if (o > w) w = o;
            }
            if (best == w) {
                unsigned long long nb = 0ULL;
#pragma unroll
                for (int i = 0; i < 16; ++i)
                    if ((avail >> i) & 1u) {
                        int j = (i >> 2) * 256 + lane * 4 + (i & 3);
                        unsigned long long k64 =
                            ((unsigned long long)kb[i] << 32) | (unsigned int)(~j);
                        if (k64 == w) { winmask |= 1u << i; avail &= ~(1u << i); }
                        else nb = k64 > nb ? k64 : nb;
                    }
                best = nb;
            }
        }
    }

    if (lane == 0) wcnt = 0;
#pragma unroll
    for (int i = 0; i < 16; ++i) {
        bool wn = ((kb[i] >> 8) > prefix) || ((winmask >> i) & 1u);
        if (wn) {
            unsigned slot = atomicAdd(&wcnt, 1u);
            int j = (i >> 2) * 256 + lane * 4 + (i & 3);
            tidx[(size_t)rb * 32 + slot] = (unsigned int)j;
            tval[(size_t)rb * 32 + slot] = __expf(v[i] - rmax) / rsum;
        }
    }
}

// ---------------- final pass A: out-branch gathered dots (R10 form) ----------
__global__ __launch_bounds__(256) void finalA_k(
    const float* __restrict__ x, const float* __restrict__ wT,
    const unsigned int* __restrict__ tidx, const float* __restrict__ tval,
    float* __restrict__ dres) {
    int n = blockIdx.x, t = threadIdx.x, wave = t >> 6, lane = t & 63;
    __shared__ float xr[1024];
    __shared__ unsigned int gidx[32]; __shared__ float gval[32];

    ((float4*)xr)[t] = ((const float4*)(x + (size_t)n * 1024))[t];
    if (t < 32) {
        gidx[t] = tidx[(size_t)n * 32 + t];
        gval[t] = tval[(size_t)n * 32 + t];
    }
    __syncthreads();

    const float4* xr4 = (const float4*)xr;
#pragma unroll
    for (int d8 = 0; d8 < 8; ++d8) {
        int d = wave * 8 + d8;
        const float4* wrow = (const float4*)(wT + (size_t)gidx[d] * 1024);
        float s = 0.f;
#pragma unroll
        for (int q = 0; q < 4; ++q) {
            float4 a = wrow[q * 64 + lane];
            float4 b = xr4[q * 64 + lane];
            s += a.x * b.x + a.y * b.y + a.z * b.z + a.w * b.w;
        }
#pragma unroll
        for (int sft = 32; sft; sft >>= 1) s += __shfl_xor(s, sft);
        if (lane == 0) dres[(size_t)n * 32 + d] = s * gval[d];
    }
}

// ---------------- final pass B: in-branch axpys + assemble (R10 form) --------
__global__ __launch_bounds__(256) void finalB_k(
    const float* __restrict__ x, const float* __restrict__ W,
    const float* __restrict__ bias,
    const unsigned int* __restrict__ tidx, const float* __restrict__ tval,
    const float* __restrict__ dres, float* __restrict__ out) {
    int n = blockIdx.x, t = threadIdx.x;
    __shared__ float xr[1024];
    __shared__ unsigned int iidx[32]; __shared__ float ival[32];
    __shared__ unsigned int gidx[32]; __shared__ float dr[32];

    if (t < 32) {
        unsigned c = tidx[((size_t)4096 + n) * 32 + t];
        iidx[t] = c;
        ival[t] = tval[((size_t)4096 + n) * 32 + t] * x[(size_t)n * 1024 + c];
    } else if (t < 64) {
        int k = t - 32;
        gidx[k] = tidx[(size_t)n * 32 + k];
        dr[k]   = dres[(size_t)n * 32 + k];
    }
    __syncthreads();

    float4 acc = ((const float4*)bias)[t];
    for (int k = 0; k < 32; ++k) {
        float g = ival[k];
        unsigned int c = iidx[k];
        float4 wr = ((const float4*)(W + (size_t)c * 1024))[t];
        acc.x = fmaf(g, wr.x, acc.x); acc.y = fmaf(g, wr.y, acc.y);
        acc.z = fmaf(g, wr.z, acc.z); acc.w = fmaf(g, wr.w, acc.w);
    }
    ((float4*)xr)[t] = acc;
    __syncthreads();
    if (t < 32) xr[gidx[t]] += dr[t];  // unique indices, no race
    __syncthreads();
    ((float4*)(out + (size_t)n * 1024))[t] = ((float4*)xr)[t];
}

extern "C" void kernel_launch(void* const* d_in, const int* in_sizes, int n_in,
                              void* d_out, int out_size, void* d_ws, size_t ws_size,
                              hipStream_t stream) {
    (void)in_sizes; (void)n_in; (void)out_size; (void)ws_size;
    const float* x        = (const float*)d_in[0];
    const float* W        = (const float*)d_in[1];
    const float* bias     = (const float*)d_in[2];
    const float* so_cw    = (const float*)d_in[3];
    const float* so_cb    = (const float*)d_in[4];
    const float* so_gm    = (const float*)d_in[5];
    const float* so_bt    = (const float*)d_in[6];
    const float* so_lw    = (const float*)d_in[7];
    const float* so_lb    = (const float*)d_in[8];
    const float* si_cw    = (const float*)d_in[9];
    const float* si_cb    = (const float*)d_in[10];
    const float* si_gm    = (const float*)d_in[11];
    const float* si_bt    = (const float*)d_in[12];
    const float* si_lw    = (const float*)d_in[13];
    const float* si_lb    = (const float*)d_in[14];
    float* out = (float*)d_out;

    float* ws       = (float*)d_ws;
    float* wT       = ws;                       // 1048576
    unsigned short* whl = (unsigned short*)(ws + 1048576);  // 1048576 ushorts
    float* xc       = ws + 1572864;             // 2 x 1048576
    float* partials = ws + 3670016;             // 262144
    float* sc       = ws + 3932160;             // 1024
    float* logits   = ws + 3933184;             // 8388608
    unsigned int* tidx = (unsigned int*)(ws + 12321792);  // 262144
    float* tval     = ws + 12583936;            // 262144
    float* dres     = ws + 12846080;            // 131072
    unsigned short* xah = (unsigned short*)(ws + 12977152);  // 2097152 ushorts
    unsigned short* xal = (unsigned short*)(ws + 14025728);  // 2097152 ushorts

    prep_k<<<1536, 256, 0, stream>>>(W, so_lw, si_lw, x, so_cw, so_cb, si_cw, si_cb,
                                     wT, whl, xc, partials);
    stats_k<<<2, 256, 0, stream>>>(partials, so_gm, so_bt, si_gm, si_bt, sc);
    gelusplit_k<<<1024, 256, 0, stream>>>(xc, sc, xah, xal);
    logits_mfma2_k<<<dim3(64, 4, 2), 256, 0, stream>>>(xah, xal, whl, so_lb, si_lb, logits);
    topk_k<<<8192, 64, 0, stream>>>(logits, tidx, tval);
    finalA_k<<<4096, 256, 0, stream>>>(x, wT, tidx, tval, dres);
    finalB_k<<<4096, 256, 0, stream>>>(x, W, bias, tidx, tval, dres, out);
}

// Round 13
// 118.850 us; speedup vs baseline: 1.2317x; 1.0788x over previous
//
#include <hip/hip_runtime.h>
#include <hip/hip_fp16.h>
#include <math.h>

// Problem: B=4, L=1024, C1=1024, C2=1024, K=32, K_IN=32, g=256.
// N = B*L = 4096 rows. All f32.
//
// ws layout (floats):
//   wT16    [524288 f32-equiv]     off 0        (fp16 W^T, 2MB, final gathers)
//   W16     [524288 f32-equiv]     off 524288   (fp16 W, 2MB, final gathers)
//   whl     [524288 f32-equiv]     off 1048576  (bf16 hi/lo split lin_w, 2MB)
//   xc      [2][4096*256]          off 1572864
//   partials[256][4][256]          off 3670016
//   sc      [2][2][256]            off 3932160
//   logits  [8192][1024]           off 3933184
//   tidx    [8192][32] (u32)       off 12321792
//   tval    [8192][32]             off 12583936
//   xah     [1048576 f32-equiv]    off 12977152 (bf16 hi xa frags, 4MB)
//   xal     [1048576 f32-equiv]    off 14025728 (bf16 lo xa frags, 4MB)
// total ~15.1M floats = 60.3 MB

typedef __attribute__((ext_vector_type(8))) short short8;
typedef __attribute__((ext_vector_type(4))) float f32x4;

__device__ __forceinline__ unsigned int ford(float f) {
    unsigned int b = __float_as_uint(f);
    return (b & 0x80000000u) ? ~b : (b | 0x80000000u);
}

// ---------------- fused prep: W->fp16 (straight+transposed) + lin_w split ----
// blocks [0,1024): W 32x32 tile -> W16 (straight) + wT16 (transposed), fp16
// blocks [1024,1280): split so/si lin_w into bf16 hi/lo MFMA B-fragments
// blocks [1280,1536): grouped conv (both branches) + BN partial stats
__global__ __launch_bounds__(256) void prep_k(
    const float* __restrict__ W,
    const float* __restrict__ so_lw, const float* __restrict__ si_lw,
    const float* __restrict__ x,
    const float* __restrict__ so_cw, const float* __restrict__ so_cb,
    const float* __restrict__ si_cw, const float* __restrict__ si_cb,
    __half* __restrict__ wT16, __half* __restrict__ W16,
    unsigned short* __restrict__ whl,
    float* __restrict__ xc, float* __restrict__ partials) {
    int bid = blockIdx.x;
    int t = threadIdx.x;
    if (bid < 1024) {
        __shared__ float tile[32][33];
        int c0 = (bid & 31) * 32, r0 = (bid >> 5) * 32;
        int tx = t & 31, ty = t >> 5;  // ty 0..7
#pragma unroll
        for (int i = 0; i < 32; i += 8) {
            float v = W[(size_t)(r0 + ty + i) * 1024 + c0 + tx];
            tile[ty + i][tx] = v;
            W16[(size_t)(r0 + ty + i) * 1024 + c0 + tx] = __float2half_rn(v);
        }
        __syncthreads();
#pragma unroll
        for (int i = 0; i < 32; i += 8)
            wT16[(size_t)(c0 + ty + i) * 1024 + r0 + tx] =
                __float2half_rn(tile[tx][ty + i]);
    } else if (bid < 1280) {
        int g = (bid - 1024) * 256 + t;  // 0..65535
        int br = g >> 15;
        int rem = g & 32767;
        int ct = rem >> 9;
        int kt = (rem >> 6) & 7;
        int l  = rem & 63;
        int col = ct * 16 + (l & 15);
        int ks  = kt * 32 + (l >> 4) * 8;
        const float* lw = (br ? si_lw : so_lw) + (size_t)col * 256 + ks;
        float4 v0 = *(const float4*)lw;
        float4 v1 = *(const float4*)(lw + 4);
        unsigned hh[8], ll[8];
#pragma unroll
        for (int j = 0; j < 8; ++j) {
            float a = j < 4 ? (&v0.x)[j] : (&v1.x)[j - 4];
            unsigned b = __float_as_uint(a);
            unsigned rh = (b + 0x7FFFu + ((b >> 16) & 1u)) & 0xFFFF0000u;
            hh[j] = rh >> 16;
            float res = a - __uint_as_float(rh);
            unsigned c = __float_as_uint(res);
            unsigned rl = (c + 0x7FFFu + ((c >> 16) & 1u)) & 0xFFFF0000u;
            ll[j] = rl >> 16;
        }
        uint4 ph, pl;
        ph.x = hh[0] | (hh[1] << 16); ph.y = hh[2] | (hh[3] << 16);
        ph.z = hh[4] | (hh[5] << 16); ph.w = hh[6] | (hh[7] << 16);
        pl.x = ll[0] | (ll[1] << 16); pl.y = ll[2] | (ll[3] << 16);
        pl.z = ll[4] | (ll[5] << 16); pl.w = ll[6] | (ll[7] << 16);
        size_t base = (((((size_t)br * 2 + 0) * 64 + ct) * 8 + kt) * 64 + l) * 8;
        size_t hstride = (size_t)64 * 8 * 64 * 8;
        *(uint4*)&whl[base]           = ph;
        *(uint4*)&whl[base + hstride] = pl;
    } else {
        int g = t;                     // channel 0..255
        int n0 = (bid - 1280) * 16;    // 256 blocks x 16 rows
        float4 wo = ((const float4*)so_cw)[g]; float bo = so_cb[g];
        float4 wi = ((const float4*)si_cw)[g]; float bi = si_cb[g];
        float so_s = 0.f, so_q = 0.f, si_s = 0.f, si_q = 0.f;
#pragma unroll
        for (int r = 0; r < 16; ++r) {
            int n = n0 + r;
            float4 xv = ((const float4*)x)[n * 256 + g];
            float co = fmaf(xv.x, wo.x, fmaf(xv.y, wo.y, fmaf(xv.z, wo.z, fmaf(xv.w, wo.w, bo))));
            float ci = fmaf(xv.x, wi.x, fmaf(xv.y, wi.y, fmaf(xv.z, wi.z, fmaf(xv.w, wi.w, bi))));
            xc[n * 256 + g] = co;
            xc[1048576 + n * 256 + g] = ci;
            so_s += co; so_q += co * co;
            si_s += ci; si_q += ci * ci;
        }
        int b = bid - 1280;
        partials[(b * 4 + 0) * 256 + g] = so_s;
        partials[(b * 4 + 1) * 256 + g] = so_q;
        partials[(b * 4 + 2) * 256 + g] = si_s;
        partials[(b * 4 + 3) * 256 + g] = si_q;
    }
}

// ---------------- finalize BN stats -> per-channel scale/shift ---------------
__global__ __launch_bounds__(256) void stats_k(
    const float* __restrict__ partials,
    const float* __restrict__ g_so, const float* __restrict__ b_so,
    const float* __restrict__ g_si, const float* __restrict__ b_si,
    float* __restrict__ sc) {
    int g = threadIdx.x;
    int br = blockIdx.x;  // 0 = so, 1 = si
    float s = 0.f, q = 0.f;
    for (int b = 0; b < 256; ++b) {
        s += partials[(b * 4 + br * 2 + 0) * 256 + g];
        q += partials[(b * 4 + br * 2 + 1) * 256 + g];
    }
    float mean = s * (1.f / 4096.f);
    float var  = q * (1.f / 4096.f) - mean * mean;  // biased, matches ref
    float rstd = rsqrtf(var + 1e-5f);
    float gm = br ? g_si[g] : g_so[g];
    float bt = br ? b_si[g] : b_so[g];
    float scale = gm * rstd;
    sc[br * 512 + g]       = scale;
    sc[br * 512 + 256 + g] = fmaf(-mean, scale, bt);
}

// ---------------- BN + exact GELU + bf16 hi/lo split -> xa MFMA A-fragments --
__global__ __launch_bounds__(256) void gelusplit_k(
    const float* __restrict__ xc, const float* __restrict__ sc,
    unsigned short* __restrict__ xah, unsigned short* __restrict__ xal) {
    int s = blockIdx.x * 256 + threadIdx.x;  // 0..262143
    int br  = s >> 17;
    int rem = s & 131071;
    int rtg = rem >> 9;
    int kt  = (rem >> 6) & 7;
    int l   = rem & 63;
    int row = rtg * 16 + (l & 15);
    int ks  = kt * 32 + (l >> 4) * 8;
    const float* xp  = xc + (size_t)br * 1048576 + (size_t)row * 256 + ks;
    const float* scp = sc + br * 512;
    float4 c0 = *(const float4*)xp;
    float4 c1 = *(const float4*)(xp + 4);
    float4 s0 = *(const float4*)(scp + ks);
    float4 s1 = *(const float4*)(scp + ks + 4);
    float4 h0 = *(const float4*)(scp + 256 + ks);
    float4 h1 = *(const float4*)(scp + 256 + ks + 4);
    unsigned hh[8], ll[8];
#pragma unroll
    for (int j = 0; j < 8; ++j) {
        float cv  = j < 4 ? (&c0.x)[j] : (&c1.x)[j - 4];
        float scl = j < 4 ? (&s0.x)[j] : (&s1.x)[j - 4];
        float shf = j < 4 ? (&h0.x)[j] : (&h1.x)[j - 4];
        float z = fmaf(cv, scl, shf);
        float a = 0.5f * z * (1.f + erff(z * 0.70710678f));
        unsigned b = __float_as_uint(a);
        unsigned rh = (b + 0x7FFFu + ((b >> 16) & 1u)) & 0xFFFF0000u;
        hh[j] = rh >> 16;
        float res = a - __uint_as_float(rh);
        unsigned cc = __float_as_uint(res);
        unsigned rl = (cc + 0x7FFFu + ((cc >> 16) & 1u)) & 0xFFFF0000u;
        ll[j] = rl >> 16;
    }
    uint4 ph, pl;
    ph.x = hh[0] | (hh[1] << 16); ph.y = hh[2] | (hh[3] << 16);
    ph.z = hh[4] | (hh[5] << 16); ph.w = hh[6] | (hh[7] << 16);
    pl.x = ll[0] | (ll[1] << 16); pl.y = ll[2] | (ll[3] << 16);
    pl.z = ll[4] | (ll[5] << 16); pl.w = ll[6] | (ll[7] << 16);
    *(uint4*)&xah[(size_t)s * 8] = ph;
    *(uint4*)&xal[(size_t)s * 8] = pl;
}

// ---------------- bf16x4-split MFMA logits GEMM (no LDS, no GELU) ------------
__global__ __launch_bounds__(256, 2) void logits_mfma2_k(
    const unsigned short* __restrict__ xah, const unsigned short* __restrict__ xal,
    const unsigned short* __restrict__ whl,
    const float* __restrict__ so_lb, const float* __restrict__ si_lb,
    float* __restrict__ logits) {
    int t = threadIdx.x;
    int bx = blockIdx.x;          // 64-row block
    int n0 = bx * 64;
    int cb = blockIdx.y;          // 256-col block
    int br = blockIdx.z;
    int wave = t >> 6, lane = t & 63;

    f32x4 acc[4][4];  // [ci][rt]
#pragma unroll
    for (int ci = 0; ci < 4; ++ci)
#pragma unroll
        for (int rt = 0; rt < 4; ++rt) acc[ci][rt] = (f32x4){0.f, 0.f, 0.f, 0.f};

    const size_t hstride = (size_t)64 * 8 * 64 * 8;
#pragma unroll 2
    for (int kt = 0; kt < 8; ++kt) {
        short8 Ah[4], Al[4];
#pragma unroll
        for (int rt = 0; rt < 4; ++rt) {
            size_t aoff = (((size_t)br * 256 + bx * 4 + rt) * 8 + kt) * 512 +
                          (size_t)lane * 8;
            Ah[rt] = *(const short8*)&xah[aoff];
            Al[rt] = *(const short8*)&xal[aoff];
        }
#pragma unroll
        for (int ci = 0; ci < 4; ++ci) {
            int ctg = cb * 16 + wave * 4 + ci;
            size_t boff = ((((size_t)br * 2 + 0) * 64 + ctg) * 8 + kt) * 512 +
                          (size_t)lane * 8;
            short8 Wh = *(const short8*)&whl[boff];
            short8 Wl = *(const short8*)&whl[boff + hstride];
#pragma unroll
            for (int rt = 0; rt < 4; ++rt) {
                acc[ci][rt] = __builtin_amdgcn_mfma_f32_16x16x32_bf16(Ah[rt], Wh, acc[ci][rt], 0, 0, 0);
                acc[ci][rt] = __builtin_amdgcn_mfma_f32_16x16x32_bf16(Ah[rt], Wl, acc[ci][rt], 0, 0, 0);
                acc[ci][rt] = __builtin_amdgcn_mfma_f32_16x16x32_bf16(Al[rt], Wh, acc[ci][rt], 0, 0, 0);
                acc[ci][rt] = __builtin_amdgcn_mfma_f32_16x16x32_bf16(Al[rt], Wl, acc[ci][rt], 0, 0, 0);
            }
        }
    }

    // C/D mapping (HW-verified): col = lane&15, row = (lane>>4)*4 + i
    const float* lb = br ? si_lb : so_lb;
#pragma unroll
    for (int ci = 0; ci < 4; ++ci) {
        int colg = cb * 256 + (wave * 4 + ci) * 16 + (lane & 15);
        float lbv = lb[colg];
#pragma unroll
        for (int rt = 0; rt < 4; ++rt) {
#pragma unroll
            for (int i = 0; i < 4; ++i) {
                int row = n0 + rt * 16 + (lane >> 4) * 4 + i;
                logits[((size_t)br * 4096 + row) * 1024 + colg] = acc[ci][rt][i] + lbv;
            }
        }
    }
}

// ---------------- softmax stats + exact top-32, one wave per row-branch ------
__global__ __launch_bounds__(64) void topk_k(const float* __restrict__ logits,
                                             unsigned int* __restrict__ tidx,
                                             float* __restrict__ tval) {
    __shared__ unsigned int hist[256];
    __shared__ unsigned int wcnt;
    int lane = threadIdx.x;
    int rb = blockIdx.x;  // 0..8191
    unsigned int* h = hist;

    const float4* lg = (const float4*)(logits + (size_t)rb * 1024);
    float v[16];
#pragma unroll
    for (int q = 0; q < 4; ++q) {
        float4 f = lg[q * 64 + lane];
        v[q * 4 + 0] = f.x; v[q * 4 + 1] = f.y;
        v[q * 4 + 2] = f.z; v[q * 4 + 3] = f.w;
    }
    float rmax = v[0];
#pragma unroll
    for (int i = 1; i < 16; ++i) rmax = fmaxf(rmax, v[i]);
#pragma unroll
    for (int s = 32; s; s >>= 1) rmax = fmaxf(rmax, __shfl_xor(rmax, s));
    float rsum = 0.f;
#pragma unroll
    for (int i = 0; i < 16; ++i) rsum += __expf(v[i] - rmax);
#pragma unroll
    for (int s = 32; s; s >>= 1) rsum += __shfl_xor(rsum, s);

    unsigned int kb[16];
#pragma unroll
    for (int i = 0; i < 16; ++i) kb[i] = ford(v[i]);

    unsigned inmask = 0xFFFFu;
    unsigned need = 32, prefix = 0, lasth = 0;
#pragma unroll
    for (int level = 0; level < 3; ++level) {
        int shift = 24 - level * 8;
        ((uint4*)h)[lane] = make_uint4(0u, 0u, 0u, 0u);
        __syncthreads();
#pragma unroll
        for (int i = 0; i < 16; ++i)
            if ((inmask >> i) & 1u) atomicAdd(&h[(kb[i] >> shift) & 0xFFu], 1u);
        __syncthreads();
        uint4 hv = ((const uint4*)h)[lane];
        unsigned sl = hv.x + hv.y + hv.z + hv.w;
        unsigned S = sl;
#pragma unroll
        for (int off = 1; off < 64; off <<= 1) {
            unsigned o = __shfl_down(S, off);
            if (lane + off < 64) S += o;
        }
        unsigned above = S - sl;
        unsigned cg3 = above + hv.w;
        unsigned cg2 = cg3 + hv.z;
        unsigned cg1 = cg2 + hv.y;
        unsigned cg0 = cg1 + hv.x;
        unsigned pack = 0;
        if      (cg3 >= need) pack = ((4u * lane + 3u) << 12) | cg3;
        else if (cg2 >= need) pack = ((4u * lane + 2u) << 12) | cg2;
        else if (cg1 >= need) pack = ((4u * lane + 1u) << 12) | cg1;
        else if (cg0 >= need) pack = ((4u * lane + 0u) << 12) | cg0;
#pragma unroll
        for (int s = 32; s; s >>= 1) {
            unsigned o = __shfl_xor(pack, s);
            pack = o > pack ? o : pack;
        }
        unsigned bstar = pack >> 12, cstar = pack & 0xFFFu;
        unsigned hstar = h[bstar];
        need -= (cstar - hstar);
        prefix = (prefix << 8) | bstar;
        lasth = hstar;
        unsigned nm = 0;
#pragma unroll
        for (int i = 0; i < 16; ++i)
            if (((inmask >> i) & 1u) && ((kb[i] >> shift) & 0xFFu) == bstar)
                nm |= 1u << i;
        inmask = nm;
        __syncthreads();
    }

    unsigned winmask = 0;
    if (lasth == need) {
        winmask = inmask;
    } else {
        unsigned avail = inmask;
        unsigned long long best = 0ULL;
#pragma unroll
        for (int i = 0; i < 16; ++i)
            if ((avail >> i) & 1u) {
                int j = (i >> 2) * 256 + lane * 4 + (i & 3);
                unsigned long long k64 =
                    ((unsigned long long)kb[i] << 32) | (unsigned int)(~j);
                best = k64 > best ? k64 : best;
            }
        for (unsigned k = 0; k < need; ++k) {
            unsigned long long w = best;
#pragma unroll
            for (int s = 32; s; s >>= 1) {
                unsigned long long o = __shfl_xor(w, s);
                if (o > w) w = o;
            }
            if (best == w) {
                unsigned long long nb = 0ULL;
#pragma unroll
                for (int i = 0; i < 16; ++i)
                    if ((avail >> i) & 1u) {
                        int j = (i >> 2) * 256 + lane * 4 + (i & 3);
                        unsigned long long k64 =
                            ((unsigned long long)kb[i] << 32) | (unsigned int)(~j);
                        if (k64 == w) { winmask |= 1u << i; avail &= ~(1u << i); }
                        else nb = k64 > nb ? k64 : nb;
                    }
                best = nb;
            }
        }
    }

    if (lane == 0) wcnt = 0;
#pragma unroll
    for (int i = 0; i < 16; ++i) {
        bool wn = ((kb[i] >> 8) > prefix) || ((winmask >> i) & 1u);
        if (wn) {
            unsigned slot = atomicAdd(&wcnt, 1u);
            int j = (i >> 2) * 256 + lane * 4 + (i & 3);
            tidx[(size_t)rb * 32 + slot] = (unsigned int)j;
            tval[(size_t)rb * 32 + slot] = __expf(v[i] - rmax) / rsum;
        }
    }
}

// ---------------- fused final: fp16 weight gathers (half the gather bytes) ---
// out[n,:] = bias + sum_k ival_k*W16[iidx_k,:] + scatter(gval_d * x.wT16[gidx_d])
__global__ __launch_bounds__(256) void final16_k(
    const float* __restrict__ x, const __half* __restrict__ wT16,
    const __half* __restrict__ W16, const float* __restrict__ bias,
    const unsigned int* __restrict__ tidx, const float* __restrict__ tval,
    float* __restrict__ out) {
    int n = blockIdx.x, t = threadIdx.x, wave = t >> 6, lane = t & 63;
    __shared__ float xr[1024];
    __shared__ float dres[32];
    __shared__ unsigned int gidx[32]; __shared__ float gval[32];
    __shared__ unsigned int iidx[32]; __shared__ float ival[32];

    ((float4*)xr)[t] = ((const float4*)(x + (size_t)n * 1024))[t];
    if (t < 32) {
        gidx[t] = tidx[(size_t)n * 32 + t];
        gval[t] = tval[(size_t)n * 32 + t];
    } else if (t < 64) {
        int k = t - 32;
        iidx[k] = tidx[((size_t)4096 + n) * 32 + k];
        ival[k] = tval[((size_t)4096 + n) * 32 + k];
    }
    __syncthreads();  // B1

    if (t < 32) ival[t] *= xr[iidx[t]];  // g_k = s_v_in * x[c_k]

    // out-branch: 32 gathered fp16 dot products, 8 per wave
    const float4* xr4 = (const float4*)xr;
#pragma unroll
    for (int d8 = 0; d8 < 8; ++d8) {
        int d = wave * 8 + d8;
        const uint4* wrow = (const uint4*)(wT16 + (size_t)gidx[d] * 1024);
        float s = 0.f;
#pragma unroll
        for (int q = 0; q < 2; ++q) {
            int idx = q * 64 + lane;          // 8 halves per load
            uint4 wv = wrow[idx];
            float4 xa = xr4[idx * 2];
            float4 xb = xr4[idx * 2 + 1];
            float2 f0 = __half22float2(*(const __half2*)&wv.x);
            float2 f1 = __half22float2(*(const __half2*)&wv.y);
            float2 f2 = __half22float2(*(const __half2*)&wv.z);
            float2 f3 = __half22float2(*(const __half2*)&wv.w);
            s += xa.x * f0.x + xa.y * f0.y + xa.z * f1.x + xa.w * f1.y +
                 xb.x * f2.x + xb.y * f2.y + xb.z * f3.x + xb.w * f3.y;
        }
#pragma unroll
        for (int sft = 32; sft; sft >>= 1) s += __shfl_xor(s, sft);
        if (lane == 0) dres[d] = s * gval[d];
    }
    __syncthreads();  // B2: ival final, dres written, xr reads done

    // in-branch + bias: 32 fp16 axpys, thread t owns cols 4t..4t+3
    float4 acc = ((const float4*)bias)[t];
    for (int k = 0; k < 32; ++k) {
        float g = ival[k];
        unsigned int c = iidx[k];
        uint2 wv = ((const uint2*)(W16 + (size_t)c * 1024))[t];
        float2 f0 = __half22float2(*(const __half2*)&wv.x);
        float2 f1 = __half22float2(*(const __half2*)&wv.y);
        acc.x = fmaf(g, f0.x, acc.x); acc.y = fmaf(g, f0.y, acc.y);
        acc.z = fmaf(g, f1.x, acc.z); acc.w = fmaf(g, f1.y, acc.w);
    }
    ((float4*)xr)[t] = acc;
    __syncthreads();  // B3
    if (t < 32) xr[gidx[t]] += dres[t];  // unique indices, no race
    __syncthreads();  // B4
    ((float4*)(out + (size_t)n * 1024))[t] = ((float4*)xr)[t];
}

extern "C" void kernel_launch(void* const* d_in, const int* in_sizes, int n_in,
                              void* d_out, int out_size, void* d_ws, size_t ws_size,
                              hipStream_t stream) {
    (void)in_sizes; (void)n_in; (void)out_size; (void)ws_size;
    const float* x        = (const float*)d_in[0];
    const float* W        = (const float*)d_in[1];
    const float* bias     = (const float*)d_in[2];
    const float* so_cw    = (const float*)d_in[3];
    const float* so_cb    = (const float*)d_in[4];
    const float* so_gm    = (const float*)d_in[5];
    const float* so_bt    = (const float*)d_in[6];
    const float* so_lw    = (const float*)d_in[7];
    const float* so_lb    = (const float*)d_in[8];
    const float* si_cw    = (const float*)d_in[9];
    const float* si_cb    = (const float*)d_in[10];
    const float* si_gm    = (const float*)d_in[11];
    const float* si_bt    = (const float*)d_in[12];
    const float* si_lw    = (const float*)d_in[13];
    const float* si_lb    = (const float*)d_in[14];
    float* out = (float*)d_out;

    float* ws       = (float*)d_ws;
    __half* wT16    = (__half*)ws;                      // 1M halves (2MB)
    __half* W16     = (__half*)(ws + 524288);           // 1M halves (2MB)
    unsigned short* whl = (unsigned short*)(ws + 1048576);  // 1M ushorts
    float* xc       = ws + 1572864;             // 2 x 1048576
    float* partials = ws + 3670016;             // 262144
    float* sc       = ws + 3932160;             // 1024
    float* logits   = ws + 3933184;             // 8388608
    unsigned int* tidx = (unsigned int*)(ws + 12321792);  // 262144
    float* tval     = ws + 12583936;            // 262144
    unsigned short* xah = (unsigned short*)(ws + 12977152);  // 2097152 ushorts
    unsigned short* xal = (unsigned short*)(ws + 14025728);  // 2097152 ushorts

    prep_k<<<1536, 256, 0, stream>>>(W, so_lw, si_lw, x, so_cw, so_cb, si_cw, si_cb,
                                     wT16, W16, whl, xc, partials);
    stats_k<<<2, 256, 0, stream>>>(partials, so_gm, so_bt, si_gm, si_bt, sc);
    gelusplit_k<<<1024, 256, 0, stream>>>(xc, sc, xah, xal);
    logits_mfma2_k<<<dim3(64, 4, 2), 256, 0, stream>>>(xah, xal, whl, so_lb, si_lb, logits);
    topk_k<<<8192, 64, 0, stream>>>(logits, tidx, tval);
    final16_k<<<4096, 256, 0, stream>>>(x, wT16, W16, bias, tidx, tval, out);
}

// Round 14
// 111.429 us; speedup vs baseline: 1.3137x; 1.0666x over previous
//
#include <hip/hip_runtime.h>
#include <hip/hip_fp16.h>
#include <math.h>

// Problem: B=4, L=1024, C1=1024, C2=1024, K=32, K_IN=32, g=256.
// N = B*L = 4096 rows. All f32.
//
// ws layout (floats):
//   wT16    [524288 f32-equiv]     off 0        (fp16 W^T, 2MB, final gathers)
//   W16     [524288 f32-equiv]     off 524288   (fp16 W, 2MB, final gathers)
//   whl     [524288 f32-equiv]     off 1048576  (bf16 hi/lo split lin_w, 2MB)
//   xc      [2][4096*256]          off 1572864
//   partials[256][4][256]          off 3670016
//   sc      [2][2][256]            off 3932160
//   logits  [8192][1024]           off 3933184
//   xah     [1048576 f32-equiv]    off 12321792 (bf16 hi xa frags, 4MB)
//   xal     [1048576 f32-equiv]    off 13370368 (bf16 lo xa frags, 4MB)
// total ~14.4M floats = 57.7 MB

typedef __attribute__((ext_vector_type(8))) short short8;
typedef __attribute__((ext_vector_type(4))) float f32x4;

__device__ __forceinline__ unsigned int ford(float f) {
    unsigned int b = __float_as_uint(f);
    return (b & 0x80000000u) ? ~b : (b | 0x80000000u);
}

// ---------------- fused prep: W->fp16 (straight+transposed) + lin_w split ----
__global__ __launch_bounds__(256) void prep_k(
    const float* __restrict__ W,
    const float* __restrict__ so_lw, const float* __restrict__ si_lw,
    const float* __restrict__ x,
    const float* __restrict__ so_cw, const float* __restrict__ so_cb,
    const float* __restrict__ si_cw, const float* __restrict__ si_cb,
    __half* __restrict__ wT16, __half* __restrict__ W16,
    unsigned short* __restrict__ whl,
    float* __restrict__ xc, float* __restrict__ partials) {
    int bid = blockIdx.x;
    int t = threadIdx.x;
    if (bid < 1024) {
        __shared__ float tile[32][33];
        int c0 = (bid & 31) * 32, r0 = (bid >> 5) * 32;
        int tx = t & 31, ty = t >> 5;  // ty 0..7
#pragma unroll
        for (int i = 0; i < 32; i += 8) {
            float v = W[(size_t)(r0 + ty + i) * 1024 + c0 + tx];
            tile[ty + i][tx] = v;
            W16[(size_t)(r0 + ty + i) * 1024 + c0 + tx] = __float2half_rn(v);
        }
        __syncthreads();
#pragma unroll
        for (int i = 0; i < 32; i += 8)
            wT16[(size_t)(c0 + ty + i) * 1024 + r0 + tx] =
                __float2half_rn(tile[tx][ty + i]);
    } else if (bid < 1280) {
        int g = (bid - 1024) * 256 + t;  // 0..65535
        int br = g >> 15;
        int rem = g & 32767;
        int ct = rem >> 9;
        int kt = (rem >> 6) & 7;
        int l  = rem & 63;
        int col = ct * 16 + (l & 15);
        int ks  = kt * 32 + (l >> 4) * 8;
        const float* lw = (br ? si_lw : so_lw) + (size_t)col * 256 + ks;
        float4 v0 = *(const float4*)lw;
        float4 v1 = *(const float4*)(lw + 4);
        unsigned hh[8], ll[8];
#pragma unroll
        for (int j = 0; j < 8; ++j) {
            float a = j < 4 ? (&v0.x)[j] : (&v1.x)[j - 4];
            unsigned b = __float_as_uint(a);
            unsigned rh = (b + 0x7FFFu + ((b >> 16) & 1u)) & 0xFFFF0000u;
            hh[j] = rh >> 16;
            float res = a - __uint_as_float(rh);
            unsigned c = __float_as_uint(res);
            unsigned rl = (c + 0x7FFFu + ((c >> 16) & 1u)) & 0xFFFF0000u;
            ll[j] = rl >> 16;
        }
        uint4 ph, pl;
        ph.x = hh[0] | (hh[1] << 16); ph.y = hh[2] | (hh[3] << 16);
        ph.z = hh[4] | (hh[5] << 16); ph.w = hh[6] | (hh[7] << 16);
        pl.x = ll[0] | (ll[1] << 16); pl.y = ll[2] | (ll[3] << 16);
        pl.z = ll[4] | (ll[5] << 16); pl.w = ll[6] | (ll[7] << 16);
        size_t base = (((((size_t)br * 2 + 0) * 64 + ct) * 8 + kt) * 64 + l) * 8;
        size_t hstride = (size_t)64 * 8 * 64 * 8;
        *(uint4*)&whl[base]           = ph;
        *(uint4*)&whl[base + hstride] = pl;
    } else {
        int g = t;                     // channel 0..255
        int n0 = (bid - 1280) * 16;    // 256 blocks x 16 rows
        float4 wo = ((const float4*)so_cw)[g]; float bo = so_cb[g];
        float4 wi = ((const float4*)si_cw)[g]; float bi = si_cb[g];
        float so_s = 0.f, so_q = 0.f, si_s = 0.f, si_q = 0.f;
#pragma unroll
        for (int r = 0; r < 16; ++r) {
            int n = n0 + r;
            float4 xv = ((const float4*)x)[n * 256 + g];
            float co = fmaf(xv.x, wo.x, fmaf(xv.y, wo.y, fmaf(xv.z, wo.z, fmaf(xv.w, wo.w, bo))));
            float ci = fmaf(xv.x, wi.x, fmaf(xv.y, wi.y, fmaf(xv.z, wi.z, fmaf(xv.w, wi.w, bi))));
            xc[n * 256 + g] = co;
            xc[1048576 + n * 256 + g] = ci;
            so_s += co; so_q += co * co;
            si_s += ci; si_q += ci * ci;
        }
        int b = bid - 1280;
        partials[(b * 4 + 0) * 256 + g] = so_s;
        partials[(b * 4 + 1) * 256 + g] = so_q;
        partials[(b * 4 + 2) * 256 + g] = si_s;
        partials[(b * 4 + 3) * 256 + g] = si_q;
    }
}

// ---------------- finalize BN stats -> per-channel scale/shift ---------------
__global__ __launch_bounds__(256) void stats_k(
    const float* __restrict__ partials,
    const float* __restrict__ g_so, const float* __restrict__ b_so,
    const float* __restrict__ g_si, const float* __restrict__ b_si,
    float* __restrict__ sc) {
    int g = threadIdx.x;
    int br = blockIdx.x;  // 0 = so, 1 = si
    float s = 0.f, q = 0.f;
    for (int b = 0; b < 256; ++b) {
        s += partials[(b * 4 + br * 2 + 0) * 256 + g];
        q += partials[(b * 4 + br * 2 + 1) * 256 + g];
    }
    float mean = s * (1.f / 4096.f);
    float var  = q * (1.f / 4096.f) - mean * mean;  // biased, matches ref
    float rstd = rsqrtf(var + 1e-5f);
    float gm = br ? g_si[g] : g_so[g];
    float bt = br ? b_si[g] : b_so[g];
    float scale = gm * rstd;
    sc[br * 512 + g]       = scale;
    sc[br * 512 + 256 + g] = fmaf(-mean, scale, bt);
}

// ---------------- BN + exact GELU + bf16 hi/lo split -> xa MFMA A-fragments --
__global__ __launch_bounds__(256) void gelusplit_k(
    const float* __restrict__ xc, const float* __restrict__ sc,
    unsigned short* __restrict__ xah, unsigned short* __restrict__ xal) {
    int s = blockIdx.x * 256 + threadIdx.x;  // 0..262143
    int br  = s >> 17;
    int rem = s & 131071;
    int rtg = rem >> 9;
    int kt  = (rem >> 6) & 7;
    int l   = rem & 63;
    int row = rtg * 16 + (l & 15);
    int ks  = kt * 32 + (l >> 4) * 8;
    const float* xp  = xc + (size_t)br * 1048576 + (size_t)row * 256 + ks;
    const float* scp = sc + br * 512;
    float4 c0 = *(const float4*)xp;
    float4 c1 = *(const float4*)(xp + 4);
    float4 s0 = *(const float4*)(scp + ks);
    float4 s1 = *(const float4*)(scp + ks + 4);
    float4 h0 = *(const float4*)(scp + 256 + ks);
    float4 h1 = *(const float4*)(scp + 256 + ks + 4);
    unsigned hh[8], ll[8];
#pragma unroll
    for (int j = 0; j < 8; ++j) {
        float cv  = j < 4 ? (&c0.x)[j] : (&c1.x)[j - 4];
        float scl = j < 4 ? (&s0.x)[j] : (&s1.x)[j - 4];
        float shf = j < 4 ? (&h0.x)[j] : (&h1.x)[j - 4];
        float z = fmaf(cv, scl, shf);
        float a = 0.5f * z * (1.f + erff(z * 0.70710678f));
        unsigned b = __float_as_uint(a);
        unsigned rh = (b + 0x7FFFu + ((b >> 16) & 1u)) & 0xFFFF0000u;
        hh[j] = rh >> 16;
        float res = a - __uint_as_float(rh);
        unsigned cc = __float_as_uint(res);
        unsigned rl = (cc + 0x7FFFu + ((cc >> 16) & 1u)) & 0xFFFF0000u;
        ll[j] = rl >> 16;
    }
    uint4 ph, pl;
    ph.x = hh[0] | (hh[1] << 16); ph.y = hh[2] | (hh[3] << 16);
    ph.z = hh[4] | (hh[5] << 16); ph.w = hh[6] | (hh[7] << 16);
    pl.x = ll[0] | (ll[1] << 16); pl.y = ll[2] | (ll[3] << 16);
    pl.z = ll[4] | (ll[5] << 16); pl.w = ll[6] | (ll[7] << 16);
    *(uint4*)&xah[(size_t)s * 8] = ph;
    *(uint4*)&xal[(size_t)s * 8] = pl;
}

// ---------------- bf16x3-split MFMA logits GEMM ------------------------------
// 3 MFMAs: Ah*Wh + Ah*Wl + Al*Wh (the Al*Wl term is ~2^-18 relative --
// far below the fp16-final error already carried; selection-safe).
__global__ __launch_bounds__(256, 2) void logits_mfma2_k(
    const unsigned short* __restrict__ xah, const unsigned short* __restrict__ xal,
    const unsigned short* __restrict__ whl,
    const float* __restrict__ so_lb, const float* __restrict__ si_lb,
    float* __restrict__ logits) {
    int t = threadIdx.x;
    int bx = blockIdx.x;          // 64-row block
    int n0 = bx * 64;
    int cb = blockIdx.y;          // 256-col block
    int br = blockIdx.z;
    int wave = t >> 6, lane = t & 63;

    f32x4 acc[4][4];  // [ci][rt]
#pragma unroll
    for (int ci = 0; ci < 4; ++ci)
#pragma unroll
        for (int rt = 0; rt < 4; ++rt) acc[ci][rt] = (f32x4){0.f, 0.f, 0.f, 0.f};

    const size_t hstride = (size_t)64 * 8 * 64 * 8;
#pragma unroll 2
    for (int kt = 0; kt < 8; ++kt) {
        short8 Ah[4], Al[4];
#pragma unroll
        for (int rt = 0; rt < 4; ++rt) {
            size_t aoff = (((size_t)br * 256 + bx * 4 + rt) * 8 + kt) * 512 +
                          (size_t)lane * 8;
            Ah[rt] = *(const short8*)&xah[aoff];
            Al[rt] = *(const short8*)&xal[aoff];
        }
#pragma unroll
        for (int ci = 0; ci < 4; ++ci) {
            int ctg = cb * 16 + wave * 4 + ci;
            size_t boff = ((((size_t)br * 2 + 0) * 64 + ctg) * 8 + kt) * 512 +
                          (size_t)lane * 8;
            short8 Wh = *(const short8*)&whl[boff];
            short8 Wl = *(const short8*)&whl[boff + hstride];
#pragma unroll
            for (int rt = 0; rt < 4; ++rt) {
                acc[ci][rt] = __builtin_amdgcn_mfma_f32_16x16x32_bf16(Ah[rt], Wh, acc[ci][rt], 0, 0, 0);
                acc[ci][rt] = __builtin_amdgcn_mfma_f32_16x16x32_bf16(Ah[rt], Wl, acc[ci][rt], 0, 0, 0);
                acc[ci][rt] = __builtin_amdgcn_mfma_f32_16x16x32_bf16(Al[rt], Wh, acc[ci][rt], 0, 0, 0);
            }
        }
    }

    // C/D mapping (HW-verified): col = lane&15, row = (lane>>4)*4 + i
    const float* lb = br ? si_lb : so_lb;
#pragma unroll
    for (int ci = 0; ci < 4; ++ci) {
        int colg = cb * 256 + (wave * 4 + ci) * 16 + (lane & 15);
        float lbv = lb[colg];
#pragma unroll
        for (int rt = 0; rt < 4; ++rt) {
#pragma unroll
            for (int i = 0; i < 4; ++i) {
                int row = n0 + rt * 16 + (lane >> 4) * 4 + i;
                logits[((size_t)br * 4096 + row) * 1024 + colg] = acc[ci][rt][i] + lbv;
            }
        }
    }
}

// ---------------- fused topk + final -----------------------------------------
// Block n: waves 0/1 run the radix top-32 for row-branches n (out) and 4096+n
// (in), emitting straight into LDS (no global round-trip); waves 2/3 load the
// x row. Then all 4 waves run the fp16-gather final. All 256 threads execute
// the uniform 3-level sync skeleton (divergent fallback has no barriers).
__global__ __launch_bounds__(256) void topkfinal_k(
    const float* __restrict__ logits, const float* __restrict__ x,
    const __half* __restrict__ wT16, const __half* __restrict__ W16,
    const float* __restrict__ bias, float* __restrict__ out) {
    int n = blockIdx.x, t = threadIdx.x, wave = t >> 6, lane = t & 63;
    __shared__ float xr[1024];
    __shared__ float dres[32];
    __shared__ unsigned int gidx[32]; __shared__ float gval[32];
    __shared__ unsigned int iidx[32]; __shared__ float ival[32];
    __shared__ unsigned int hist[2][256];
    __shared__ unsigned int wcnt[2];

    float v[16];
    unsigned int kb[16];
    float rmax = 0.f, rsum = 0.f;
    unsigned inmask = 0xFFFFu, need = 32, prefix = 0, lasth = 0;

    if (wave < 2) {
        const float4* lg = (const float4*)(logits + ((size_t)wave * 4096 + n) * 1024);
#pragma unroll
        for (int q = 0; q < 4; ++q) {
            float4 f = lg[q * 64 + lane];
            v[q * 4 + 0] = f.x; v[q * 4 + 1] = f.y;
            v[q * 4 + 2] = f.z; v[q * 4 + 3] = f.w;
        }
        rmax = v[0];
#pragma unroll
        for (int i = 1; i < 16; ++i) rmax = fmaxf(rmax, v[i]);
#pragma unroll
        for (int s = 32; s; s >>= 1) rmax = fmaxf(rmax, __shfl_xor(rmax, s));
#pragma unroll
        for (int i = 0; i < 16; ++i) rsum += __expf(v[i] - rmax);
#pragma unroll
        for (int s = 32; s; s >>= 1) rsum += __shfl_xor(rsum, s);
#pragma unroll
        for (int i = 0; i < 16; ++i) kb[i] = ford(v[i]);
    } else {
        int i = t - 128;  // 0..127, two float4 each
        const float4* xrow = (const float4*)(x + (size_t)n * 1024);
        ((float4*)xr)[i]       = xrow[i];
        ((float4*)xr)[i + 128] = xrow[i + 128];
    }

    // ---- 3-level radix descent (uniform sync skeleton across all waves) ----
    for (int level = 0; level < 3; ++level) {
        int shift = 24 - level * 8;
        if (wave < 2) ((uint4*)hist[wave])[lane] = make_uint4(0u, 0u, 0u, 0u);
        __syncthreads();
        if (wave < 2) {
            unsigned int* h = hist[wave];
#pragma unroll
            for (int i = 0; i < 16; ++i)
                if ((inmask >> i) & 1u) atomicAdd(&h[(kb[i] >> shift) & 0xFFu], 1u);
        }
        __syncthreads();
        if (wave < 2) {
            unsigned int* h = hist[wave];
            uint4 hv = ((const uint4*)h)[lane];
            unsigned sl = hv.x + hv.y + hv.z + hv.w;
            unsigned S = sl;
#pragma unroll
            for (int off = 1; off < 64; off <<= 1) {
                unsigned o = __shfl_down(S, off);
                if (lane + off < 64) S += o;
            }
            unsigned above = S - sl;
            unsigned cg3 = above + hv.w;
            unsigned cg2 = cg3 + hv.z;
            unsigned cg1 = cg2 + hv.y;
            unsigned cg0 = cg1 + hv.x;
            unsigned pack = 0;
            if      (cg3 >= need) pack = ((4u * lane + 3u) << 12) | cg3;
            else if (cg2 >= need) pack = ((4u * lane + 2u) << 12) | cg2;
            else if (cg1 >= need) pack = ((4u * lane + 1u) << 12) | cg1;
            else if (cg0 >= need) pack = ((4u * lane + 0u) << 12) | cg0;
#pragma unroll
            for (int s = 32; s; s >>= 1) {
                unsigned o = __shfl_xor(pack, s);
                pack = o > pack ? o : pack;
            }
            unsigned bstar = pack >> 12, cstar = pack & 0xFFFu;
            unsigned hstar = h[bstar];
            need -= (cstar - hstar);
            prefix = (prefix << 8) | bstar;
            lasth = hstar;
            unsigned nm = 0;
#pragma unroll
            for (int i = 0; i < 16; ++i)
                if (((inmask >> i) & 1u) && ((kb[i] >> shift) & 0xFFu) == bstar)
                    nm |= 1u << i;
            inmask = nm;
        }
        __syncthreads();  // protect hist reads vs next level's zeroing
    }

    if (wave < 2) {
        unsigned winmask = 0;
        if (lasth == need) {
            winmask = inmask;
        } else {
            unsigned avail = inmask;
            unsigned long long best = 0ULL;
#pragma unroll
            for (int i = 0; i < 16; ++i)
                if ((avail >> i) & 1u) {
                    int j = (i >> 2) * 256 + lane * 4 + (i & 3);
                    unsigned long long k64 =
                        ((unsigned long long)kb[i] << 32) | (unsigned int)(~j);
                    best = k64 > best ? k64 : best;
                }
            for (unsigned k = 0; k < need; ++k) {
                unsigned long long w = best;
#pragma unroll
                for (int s = 32; s; s >>= 1) {
                    unsigned long long o = __shfl_xor(w, s);
                    if (o > w) w = o;
                }
                if (best == w) {
                    unsigned long long nb = 0ULL;
#pragma unroll
                    for (int i = 0; i < 16; ++i)
                        if ((avail >> i) & 1u) {
                            int j = (i >> 2) * 256 + lane * 4 + (i & 3);
                            unsigned long long k64 =
                                ((unsigned long long)kb[i] << 32) | (unsigned int)(~j);
                            if (k64 == w) { winmask |= 1u << i; avail &= ~(1u << i); }
                            else nb = k64 > nb ? k64 : nb;
                        }
                    best = nb;
                }
            }
        }
        if (lane == 0) wcnt[wave] = 0;
        unsigned int* oid = wave ? iidx : gidx;
        float*        ovl = wave ? ival : gval;
#pragma unroll
        for (int i = 0; i < 16; ++i) {
            bool wn = ((kb[i] >> 8) > prefix) || ((winmask >> i) & 1u);
            if (wn) {
                unsigned slot = atomicAdd(&wcnt[wave], 1u);
                int j = (i >> 2) * 256 + lane * 4 + (i & 3);
                oid[slot] = (unsigned int)j;
                ovl[slot] = __expf(v[i] - rmax) / rsum;
            }
        }
    }
    __syncthreads();  // B1: topk results + xr ready

    if (t < 32) ival[t] *= xr[iidx[t]];  // g_k = s_v_in * x[c_k]

    // out-branch: 32 gathered fp16 dot products, 8 per wave
    const float4* xr4 = (const float4*)xr;
#pragma unroll
    for (int d8 = 0; d8 < 8; ++d8) {
        int d = wave * 8 + d8;
        const uint4* wrow = (const uint4*)(wT16 + (size_t)gidx[d] * 1024);
        float s = 0.f;
#pragma unroll
        for (int q = 0; q < 2; ++q) {
            int idx = q * 64 + lane;          // 8 halves per load
            uint4 wv = wrow[idx];
            float4 xa = xr4[idx * 2];
            float4 xb = xr4[idx * 2 + 1];
            float2 f0 = __half22float2(*(const __half2*)&wv.x);
            float2 f1 = __half22float2(*(const __half2*)&wv.y);
            float2 f2 = __half22float2(*(const __half2*)&wv.z);
            float2 f3 = __half22float2(*(const __half2*)&wv.w);
            s += xa.x * f0.x + xa.y * f0.y + xa.z * f1.x + xa.w * f1.y +
                 xb.x * f2.x + xb.y * f2.y + xb.z * f3.x + xb.w * f3.y;
        }
#pragma unroll
        for (int sft = 32; sft; sft >>= 1) s += __shfl_xor(s, sft);
        if (lane == 0) dres[d] = s * gval[d];
    }
    __syncthreads();  // B2: ival final, dres written, xr reads done

    // in-branch + bias: 32 fp16 axpys, thread t owns cols 4t..4t+3
    float4 acc = ((const float4*)bias)[t];
    for (int k = 0; k < 32; ++k) {
        float g = ival[k];
        unsigned int c = iidx[k];
        uint2 wv = ((const uint2*)(W16 + (size_t)c * 1024))[t];
        float2 f0 = __half22float2(*(const __half2*)&wv.x);
        float2 f1 = __half22float2(*(const __half2*)&wv.y);
        acc.x = fmaf(g, f0.x, acc.x); acc.y = fmaf(g, f0.y, acc.y);
        acc.z = fmaf(g, f1.x, acc.z); acc.w = fmaf(g, f1.y, acc.w);
    }
    ((float4*)xr)[t] = acc;
    __syncthreads();  // B3
    if (t < 32) xr[gidx[t]] += dres[t];  // unique indices, no race
    __syncthreads();  // B4
    ((float4*)(out + (size_t)n * 1024))[t] = ((float4*)xr)[t];
}

extern "C" void kernel_launch(void* const* d_in, const int* in_sizes, int n_in,
                              void* d_out, int out_size, void* d_ws, size_t ws_size,
                              hipStream_t stream) {
    (void)in_sizes; (void)n_in; (void)out_size; (void)ws_size;
    const float* x        = (const float*)d_in[0];
    const float* W        = (const float*)d_in[1];
    const float* bias     = (const float*)d_in[2];
    const float* so_cw    = (const float*)d_in[3];
    const float* so_cb    = (const float*)d_in[4];
    const float* so_gm    = (const float*)d_in[5];
    const float* so_bt    = (const float*)d_in[6];
    const float* so_lw    = (const float*)d_in[7];
    const float* so_lb    = (const float*)d_in[8];
    const float* si_cw    = (const float*)d_in[9];
    const float* si_cb    = (const float*)d_in[10];
    const float* si_gm    = (const float*)d_in[11];
    const float* si_bt    = (const float*)d_in[12];
    const float* si_lw    = (const float*)d_in[13];
    const float* si_lb    = (const float*)d_in[14];
    float* out = (float*)d_out;

    float* ws       = (float*)d_ws;
    __half* wT16    = (__half*)ws;                      // 1M halves (2MB)
    __half* W16     = (__half*)(ws + 524288);           // 1M halves (2MB)
    unsigned short* whl = (unsigned short*)(ws + 1048576);  // 1M ushorts
    float* xc       = ws + 1572864;             // 2 x 1048576
    float* partials = ws + 3670016;             // 262144
    float* sc       = ws + 3932160;             // 1024
    float* logits   = ws + 3933184;             // 8388608
    unsigned short* xah = (unsigned short*)(ws + 12321792);  // 2097152 ushorts
    unsigned short* xal = (unsigned short*)(ws + 13370368);  // 2097152 ushorts

    prep_k<<<1536, 256, 0, stream>>>(W, so_lw, si_lw, x, so_cw, so_cb, si_cw, si_cb,
                                     wT16, W16, whl, xc, partials);
    stats_k<<<2, 256, 0, stream>>>(partials, so_gm, so_bt, si_gm, si_bt, sc);
    gelusplit_k<<<1024, 256, 0, stream>>>(xc, sc, xah, xal);
    logits_mfma2_k<<<dim3(64, 4, 2), 256, 0, stream>>>(xah, xal, whl, so_lb, si_lb, logits);
    topkfinal_k<<<4096, 256, 0, stream>>>(logits, x, wT16, W16, bias, out);
}